// Round 13
// baseline (902.352 us; speedup 1.0000x reference)
//
#include <hip/hip_runtime.h>
#include <hip/hip_bf16.h>
#include <stdint.h>

#define BTOT  65536
#define KTR   11
#define NSLOT 12   // 11 transforms + z

typedef __attribute__((ext_vector_type(8))) short bf16x8_t;
typedef __attribute__((ext_vector_type(4))) float f32x4_t;

// Swizzled LDS layout: row m x 256 bf16 cols, 16B groups rotated by row so
// frag ds_read_b128 across 16 rows spreads banks (<=2-way, free per m136).
__device__ __forceinline__ int act_addr(int m, int n) {
    return m * 256 + ((((n >> 3) + m) & 31) << 3) + (n & 7);
}

// tanh-form gelu via sigmoid identity: gelu = x * rcp(1 + 2^-t2).
__device__ __forceinline__ float gelu_fast(float x) {
    float x2 = x * x;
    float t2 = 2.3022083f * x * fmaf(0.044715f, x2, 1.0f);   // 1.5957691*log2e
    float e  = exp2f(-t2);
    return x * __builtin_amdgcn_rcpf(1.0f + e);
}

// generic fp32 -> bf16 cast, 4 elems/thread (also used for Tw2 cast)
__global__ void cast_x_kernel(const float* __restrict__ x, __hip_bfloat16* __restrict__ xb) {
    int i = (blockIdx.x * 256 + threadIdx.x) * 4;
    float4 v = *(const float4*)(x + i);
    union { __hip_bfloat16 h[4]; uint64_t u; } o;
    o.h[0] = __float2bfloat16(v.x);
    o.h[1] = __float2bfloat16(v.y);
    o.h[2] = __float2bfloat16(v.z);
    o.h[3] = __float2bfloat16(v.w);
    *(uint64_t*)(xb + i) = o.u;
}

// out[b][c][r] = in[b][r][c], cast fp32 -> bf16.
__global__ void transpose_cast_kernel(const float* __restrict__ in,
                                      __hip_bfloat16* __restrict__ out,
                                      int R, int C) {
    __shared__ float tile[32][33];
    int tpc = C >> 5;
    int tr = (blockIdx.x / tpc) << 5;
    int tc = (blockIdx.x % tpc) << 5;
    const float* bi = in + (size_t)blockIdx.y * R * C;
    __hip_bfloat16* bo = out + (size_t)blockIdx.y * R * C;
    int lx = threadIdx.x & 31, ly = threadIdx.x >> 5;
    #pragma unroll
    for (int r = 0; r < 32; r += 8)
        tile[ly + r][lx] = bi[(size_t)(tr + ly + r) * C + tc + lx];
    __syncthreads();
    #pragma unroll
    for (int r = 0; r < 32; r += 8)
        bo[(size_t)(tc + ly + r) * R + tr + lx] = __float2bfloat16(tile[lx][ly + r]);
}

// Fused weight: Wft[k][j][h] = sum_d Ew1t[j][d] * Tw2b[k][h][d]
// (= (Tw2[k] @ Ew1)^T). Legal: no nonlinearity between Tw2 and Ew1 stages.
__global__ void fuse_w_kernel(const __hip_bfloat16* __restrict__ Ew1t,
                              const __hip_bfloat16* __restrict__ Tw2b,
                              __hip_bfloat16* __restrict__ Wft)
{
    __shared__ __align__(16) __hip_bfloat16 bt[64 * 256];
    const int tid  = threadIdx.x;
    const int wave = tid >> 6, lane = tid & 63;
    const int lr = lane & 15, q = lane >> 4;
    const int k  = blockIdx.y;
    const int h0 = blockIdx.x << 6;
    const __hip_bfloat16* src = Tw2b + (size_t)k * 65536;

    #pragma unroll
    for (int i = 0; i < 8; ++i) {
        int lin = i * 256 + tid;
        int r = lin >> 5, g = lin & 31;
        bf16x8_t v = *(const bf16x8_t*)(src + (size_t)(h0 + r) * 256 + g * 8);
        *(bf16x8_t*)(bt + act_addr(r, g * 8)) = v;
    }
    __syncthreads();

    const int wc = wave << 6;
    f32x4_t acc[4][4];
    #pragma unroll
    for (int mt = 0; mt < 4; ++mt)
        #pragma unroll
        for (int nt = 0; nt < 4; ++nt)
            acc[mt][nt] = (f32x4_t){0.f, 0.f, 0.f, 0.f};

    #pragma unroll 1
    for (int kc = 0; kc < 8; ++kc) {
        const int kof = (kc << 5) + (q << 3);
        bf16x8_t a[4], b[4];
        #pragma unroll
        for (int mt = 0; mt < 4; ++mt)
            a[mt] = *(const bf16x8_t*)(Ew1t + (size_t)(wc + (mt << 4) + lr) * 256 + kof);
        #pragma unroll
        for (int nt = 0; nt < 4; ++nt)
            b[nt] = *(const bf16x8_t*)(bt + act_addr((nt << 4) + lr, kof));
        #pragma unroll
        for (int mt = 0; mt < 4; ++mt)
            #pragma unroll
            for (int nt = 0; nt < 4; ++nt)
                acc[mt][nt] = __builtin_amdgcn_mfma_f32_16x16x32_bf16(a[mt], b[nt], acc[mt][nt], 0, 0, 0);
    }

    __hip_bfloat16* dst = Wft + (size_t)k * 65536;
    #pragma unroll
    for (int mt = 0; mt < 4; ++mt)
        #pragma unroll
        for (int nt = 0; nt < 4; ++nt) {
            const int h = h0 + (nt << 4) + lr;
            #pragma unroll
            for (int r = 0; r < 4; ++r) {
                const int j = wc + (mt << 4) + (q << 2) + r;
                dst[(size_t)j * 256 + h] = __float2bfloat16(acc[mt][nt][r]);
            }
        }
}

// bf[k][j] = Eb1[j] + sum_d Tb2[k][d] * Ew1[d][j]   (fp32 throughout)
__global__ void fuse_b_kernel(const float* __restrict__ Tb2,
                              const float* __restrict__ Ew1,
                              const float* __restrict__ Eb1,
                              float* __restrict__ bf)
{
    const int k = blockIdx.x, j = threadIdx.x;
    float s = Eb1[j];
    #pragma unroll 4
    for (int d = 0; d < 256; ++d)
        s = fmaf(Tb2[k * 256 + d], Ew1[d * 256 + j], s);
    bf[k * 256 + j] = s;
}

// MFMA half of a stage: acc <- bias; acc += W^T x act^T over K=256.
// a-frags (global/L2) 1-deep prefetched across kc; b-frags in-loop from LDS
// (compiler's fine-grained lgkmcnt covers them; extra b-prefetch spilled, R10).
__device__ __forceinline__ void mfma_part(const __hip_bfloat16* act,
                                          const __hip_bfloat16* __restrict__ Wt,
                                          const float* __restrict__ bias,
                                          f32x4_t acc[4][4], int lr, int q, int wc)
{
    #pragma unroll
    for (int mt = 0; mt < 4; ++mt) {
        const float4 bv = *(const float4*)(bias + wc + (mt << 4) + (q << 2));
        #pragma unroll
        for (int nt = 0; nt < 4; ++nt)
            acc[mt][nt] = (f32x4_t){bv.x, bv.y, bv.z, bv.w};
    }

    bf16x8_t a[4];
    #pragma unroll
    for (int mt = 0; mt < 4; ++mt)
        a[mt] = *(const bf16x8_t*)(Wt + (size_t)(wc + (mt << 4) + lr) * 256 + (q << 3));

    #pragma unroll 1
    for (int kc = 0; kc < 8; ++kc) {
        const int kof = (kc << 5) + (q << 3);
        bf16x8_t an[4];
        if (kc < 7) {
            #pragma unroll
            for (int mt = 0; mt < 4; ++mt)
                an[mt] = *(const bf16x8_t*)(Wt + (size_t)(wc + (mt << 4) + lr) * 256 + kof + 32);
        }
        bf16x8_t b[4];
        #pragma unroll
        for (int nt = 0; nt < 4; ++nt)
            b[nt] = *(const bf16x8_t*)(act + act_addr((nt << 4) + lr, kof));
        #pragma unroll
        for (int mt = 0; mt < 4; ++mt)
            #pragma unroll
            for (int nt = 0; nt < 4; ++nt)
                acc[mt][nt] = __builtin_amdgcn_mfma_f32_16x16x32_bf16(a[mt], b[nt], acc[mt][nt], 0, 0, 0);
        if (kc < 7) {
            #pragma unroll
            for (int mt = 0; mt < 4; ++mt) a[mt] = an[mt];
        }
    }
}

// Epilogue half: gelu/cvt/swizzled ds_write of the 64 outputs.
template<bool DO_GELU>
__device__ __forceinline__ void ep_part(__hip_bfloat16* act, f32x4_t acc[4][4],
                                        int lr, int q, int wc)
{
    #pragma unroll
    for (int mt = 0; mt < 4; ++mt) {
        const int nbase = wc + (mt << 4) + (q << 2);
        #pragma unroll
        for (int nt = 0; nt < 4; ++nt) {
            const int row = (nt << 4) + lr;
            union { __hip_bfloat16 h[4]; uint64_t u; } o;
            #pragma unroll
            for (int r = 0; r < 4; ++r) {
                float v = acc[mt][nt][r];
                if (DO_GELU) v = gelu_fast(v);
                o.h[r] = __float2bfloat16(v);
            }
            *(uint64_t*)(act + act_addr(row, nbase)) = o.u;
        }
    }
}

// Wave-role-split chain: 512 threads = 8 waves. Waves 0-3 own slot A, waves
// 4-7 own slot B; phases offset by half a stage. Every phase each SIMD hosts
// one MFMA-phase wave AND one ep-phase wave (wave i -> SIMD i&3, so groups
// land pairwise on the same SIMDs) -- m114: separate MFMA/VALU waves on one
// CU overlap fully (time = max, not sum). One acc set/thread, 2 blocks/CU x
// 8 waves = 16 waves/CU occupancy (2x R11). All __syncthreads() are outside
// the grp conditionals -- every thread reaches every barrier.
__launch_bounds__(512, 2)
__global__ void chain_kernel(const __hip_bfloat16* __restrict__ xb,
                             const __hip_bfloat16* __restrict__ Tw1t,
                             const float* __restrict__ Tb1,
                             const __hip_bfloat16* __restrict__ Wft,
                             const float* __restrict__ bfb,
                             const __hip_bfloat16* __restrict__ Ew1t,
                             const float* __restrict__ Eb1,
                             const __hip_bfloat16* __restrict__ Ew2t,
                             const float* __restrict__ Eb2,
                             __hip_bfloat16* __restrict__ zbuf,
                             int b0)
{
    __shared__ __align__(16) __hip_bfloat16 actA[64 * 256];   // 32 KB
    __shared__ __align__(16) __hip_bfloat16 actB[64 * 256];   // 32 KB
    const int tid  = threadIdx.x;
    const int wave = tid >> 6, lane = tid & 63;
    const int lr = lane & 15, q = lane >> 4;
    const int grp = wave >> 2;            // 0 = slot A group, 1 = slot B group
    const int wc  = (wave & 3) << 6;      // weight-col strip within group
    const int pair = blockIdx.y;
    const int tile = blockIdx.x;
    const int s0 = pair * 2, s1 = s0 + 1;
    const bool zp = (pair == 5);          // s1 == 11 is the z (encoder) slot
    __hip_bfloat16* act = grp ? actB : actA;

    // stage x tile into BOTH buffers (512 threads, 4 vec8 each per buffer)
    #pragma unroll
    for (int i = 0; i < 4; ++i) {
        int lin = i * 512 + tid;
        int r = lin >> 5, g = lin & 31;
        bf16x8_t v = *(const bf16x8_t*)(xb + (size_t)(b0 + tile * 64 + r) * 256 + g * 8);
        *(bf16x8_t*)(actA + act_addr(r, g * 8)) = v;
        *(bf16x8_t*)(actB + act_addr(r, g * 8)) = v;
    }
    __syncthreads();

    // per-group stage tables (wave-uniform selects, no divergence)
    const __hip_bfloat16 *W0, *W1, *W2;
    const float *B0, *B1, *B2;
    if (grp == 0) {
        W0 = Tw1t + (size_t)s0 * 65536; B0 = Tb1 + s0 * 256;
        W1 = Wft  + (size_t)s0 * 65536; B1 = bfb + s0 * 256;
        W2 = Ew2t;                      B2 = Eb2;
    } else if (!zp) {
        W0 = Tw1t + (size_t)s1 * 65536; B0 = Tb1 + s1 * 256;
        W1 = Wft  + (size_t)s1 * 65536; B1 = bfb + s1 * 256;
        W2 = Ew2t;                      B2 = Eb2;
    } else {
        W0 = Ew1t; B0 = Eb1;            // z: gelu(x@Ew1+e1) -> @Ew2+e2
        W1 = Ew2t; B1 = Eb2;
        W2 = nullptr; B2 = nullptr;     // never used (ph4/ph5 guards)
    }

    f32x4_t acc[4][4];

    // ph0: A.mfma0
    if (!grp) mfma_part(act, W0, B0, acc, lr, q, wc);
    __syncthreads();
    // ph1: A.ep0 || B.mfma0
    if (!grp) ep_part<true>(act, acc, lr, q, wc);
    else      mfma_part(act, W0, B0, acc, lr, q, wc);
    __syncthreads();
    // ph2: A.mfma1 || B.ep0
    if (!grp) mfma_part(act, W1, B1, acc, lr, q, wc);
    else      ep_part<true>(act, acc, lr, q, wc);
    __syncthreads();
    // ph3: A.ep1 || B.mfma1
    if (!grp) ep_part<true>(act, acc, lr, q, wc);
    else      mfma_part(act, W1, B1, acc, lr, q, wc);
    __syncthreads();
    // ph4: A.mfma2 || B.ep1 (T: gelu on Wf output; z: final Ew2, no gelu)
    if (!grp) mfma_part(act, W2, B2, acc, lr, q, wc);
    else if (zp) ep_part<false>(act, acc, lr, q, wc);
    else         ep_part<true >(act, acc, lr, q, wc);
    __syncthreads();
    // ph5: A.ep2 (final) || B.mfma2 (T only)
    if (!grp) ep_part<false>(act, acc, lr, q, wc);
    else if (!zp) mfma_part(act, W2, B2, acc, lr, q, wc);
    __syncthreads();
    // ph6: B.ep2 (T only, final)
    if (grp && !zp) ep_part<false>(act, acc, lr, q, wc);
    __syncthreads();

    // contiguous per-slot zbuf blobs, nontemporal (512 threads, both blobs)
    __hip_bfloat16* d0 = zbuf + (size_t)(tile * NSLOT + s0) * (64 * 256);
    __hip_bfloat16* d1 = zbuf + (size_t)(tile * NSLOT + s1) * (64 * 256);
    #pragma unroll
    for (int i = 0; i < 4; ++i) {
        int lin = i * 512 + tid;
        int r = lin >> 5, g = lin & 31;
        bf16x8_t v0 = *(const bf16x8_t*)(actA + act_addr(r, g * 8));
        __builtin_nontemporal_store(v0, (bf16x8_t*)(d0 + lin * 8));
        bf16x8_t v1 = *(const bf16x8_t*)(actB + act_addr(r, g * 8));
        __builtin_nontemporal_store(v1, (bf16x8_t*)(d1 + lin * 8));
    }
}

// Per row: G = Z Z^T (12x12 over H=256) via mfma(v,v,acc). 8 rows/wave,
// 2-deep row pipeline, rcp-for-divide tail, nontemporal blob reads.
#define ROW_BODY(V, I)                                                        \
    {                                                                         \
        f32x4_t acc = (f32x4_t){0.f, 0.f, 0.f, 0.f};                          \
        _Pragma("unroll")                                                     \
        for (int kc = 0; kc < 8; ++kc)                                        \
            acc = __builtin_amdgcn_mfma_f32_16x16x32_bf16(V[kc], V[kc], acc, 0, 0, 0); \
        _Pragma("unroll")                                                     \
        for (int rr = 0; rr < 4; ++rr)                                        \
            Gw[wave][(q << 2) + rr][lr] = acc[rr];                            \
        float term = 0.f;                                                     \
        if (lane < 11) {                                                      \
            const int k = lane;                                               \
            float nr[NSLOT];                                                  \
            _Pragma("unroll")                                                 \
            for (int l = 0; l < NSLOT; ++l)                                   \
                nr[l] = __builtin_amdgcn_rcpf(fmaxf(sqrtf(Gw[wave][l][l]), 1e-4f)); \
            const float nrk = nr[k];                                          \
            float neg = 0.f;                                                  \
            _Pragma("unroll")                                                 \
            for (int l = 0; l < KTR; ++l)                                     \
                if (l != k)                                                   \
                    neg += __expf(Gw[wave][l][k] * nr[l] * nrk);              \
            float cz = Gw[wave][KTR][k] * nr[KTR] * nrk;                      \
            term = __logf(__expf(cz) + neg) - cz;                             \
        }                                                                     \
        term += __shfl_xor(term, 1);                                          \
        term += __shfl_xor(term, 2);                                          \
        term += __shfl_xor(term, 4);                                          \
        term += __shfl_xor(term, 8);                                          \
        if (lane == 0) out[b0 + r0 + (I)] = term;                             \
    }

__launch_bounds__(256, 4)
__global__ void reduce_kernel(const __hip_bfloat16* __restrict__ zbuf,
                              float* __restrict__ out, int b0)
{
    __shared__ float Gw[4][16][17];
    const int tid  = threadIdx.x;
    const int wave = tid >> 6, lane = tid & 63;
    const int lr = lane & 15, q = lane >> 4;
    const int slot = lr < NSLOT ? lr : NSLOT - 1;   // lanes 12-15 broadcast slot 11

    const int r0   = (blockIdx.x * 4 + wave) * 8;   // 8 contiguous rows per wave
    const int tile = r0 >> 6, rloc = r0 & 63;       // all 8 rows inside one tile blob
    const __hip_bfloat16* zr = zbuf + (size_t)tile * (NSLOT * 64 * 256)
                             + (size_t)slot * (64 * 256) + rloc * 256 + (q << 3);

    bf16x8_t va[8], vb[8];
    #pragma unroll
    for (int kc = 0; kc < 8; ++kc)
        va[kc] = __builtin_nontemporal_load((const bf16x8_t*)(zr + kc * 32));

    #pragma unroll 1
    for (int i2 = 0; i2 < 4; ++i2) {
        const int ie = i2 * 2;
        {   // even row: consume va, prefetch row ie+1 into vb (always valid)
            const __hip_bfloat16* zn = zr + (ie + 1) * 256;
            #pragma unroll
            for (int kc = 0; kc < 8; ++kc)
                vb[kc] = __builtin_nontemporal_load((const bf16x8_t*)(zn + kc * 32));
            ROW_BODY(va, ie)
        }
        {   // odd row: consume vb, prefetch row ie+2 into va (guarded)
            if (ie + 2 < 8) {
                const __hip_bfloat16* zn = zr + (ie + 2) * 256;
                #pragma unroll
                for (int kc = 0; kc < 8; ++kc)
                    va[kc] = __builtin_nontemporal_load((const bf16x8_t*)(zn + kc * 32));
            }
            ROW_BODY(vb, ie + 1)
        }
    }
}

extern "C" void kernel_launch(void* const* d_in, const int* in_sizes, int n_in,
                              void* d_out, int out_size, void* d_ws, size_t ws_size,
                              hipStream_t stream)
{
    const float* x   = (const float*)d_in[0];
    const float* Tw1 = (const float*)d_in[1];
    const float* Tb1 = (const float*)d_in[2];
    const float* Tw2 = (const float*)d_in[3];
    const float* Tb2 = (const float*)d_in[4];
    const float* Ew1 = (const float*)d_in[5];
    const float* Eb1 = (const float*)d_in[6];
    const float* Ew2 = (const float*)d_in[7];
    const float* Eb2 = (const float*)d_in[8];
    float* out = (float*)d_out;

    char* ws = (char*)d_ws;
    const size_t off_xb   = 0;
    const size_t off_tw1  = off_xb   + (size_t)BTOT * 256 * 2;     // 32 MB
    const size_t off_wf   = off_tw1  + (size_t)KTR * 65536 * 2;
    const size_t off_ew1  = off_wf   + (size_t)KTR * 65536 * 2;
    const size_t off_ew2  = off_ew1  + (size_t)65536 * 2;
    const size_t off_tw2b = off_ew2  + (size_t)65536 * 2;
    const size_t off_bf   = off_tw2b + (size_t)KTR * 65536 * 2;
    const size_t off_z    = off_bf   + (size_t)KTR * 256 * 4;

    __hip_bfloat16* xb   = (__hip_bfloat16*)(ws + off_xb);
    __hip_bfloat16* Tw1t = (__hip_bfloat16*)(ws + off_tw1);
    __hip_bfloat16* Wft  = (__hip_bfloat16*)(ws + off_wf);
    __hip_bfloat16* Ew1t = (__hip_bfloat16*)(ws + off_ew1);
    __hip_bfloat16* Ew2t = (__hip_bfloat16*)(ws + off_ew2);
    __hip_bfloat16* Tw2b = (__hip_bfloat16*)(ws + off_tw2b);
    float*          bfb  = (float*)(ws + off_bf);
    __hip_bfloat16* zbuf = (__hip_bfloat16*)(ws + off_z);

    // 4-chunk split (zbuf/chunk = 100MB, L3-resident for the reduce reads).
    long long zbytes = (long long)ws_size - (long long)off_z;
    long long rows_cap = zbytes > 0 ? zbytes / ((long long)NSLOT * 256 * 2) : 0;
    int chunk = (int)((rows_cap / 128) * 128);
    if (chunk > BTOT / 4) chunk = BTOT / 4;
    if (chunk < 128) chunk = 128;

    cast_x_kernel<<<dim3(BTOT * 256 / 1024), 256, 0, stream>>>(x, xb);
    cast_x_kernel<<<dim3(KTR * 65536 / 1024), 256, 0, stream>>>(Tw2, Tw2b);
    transpose_cast_kernel<<<dim3(64, KTR), 256, 0, stream>>>(Tw1, Tw1t, 256, 256);
    transpose_cast_kernel<<<dim3(64, 1),   256, 0, stream>>>(Ew1, Ew1t, 256, 256);
    transpose_cast_kernel<<<dim3(64, 1),   256, 0, stream>>>(Ew2, Ew2t, 256, 256);
    fuse_b_kernel<<<dim3(KTR), 256, 0, stream>>>(Tb2, Ew1, Eb1, bfb);
    fuse_w_kernel<<<dim3(4, KTR), 256, 0, stream>>>(Ew1t, Tw2b, Wft);

    for (int b0 = 0; b0 < BTOT; b0 += chunk) {
        int rows = (BTOT - b0 < chunk) ? (BTOT - b0) : chunk;
        chain_kernel<<<dim3(rows / 64, NSLOT / 2), 512, 0, stream>>>(
            xb, Tw1t, Tb1, Wft, bfb, Ew1t, Eb1, Ew2t, Eb2, zbuf, b0);
        reduce_kernel<<<dim3(rows / 32), 256, 0, stream>>>(zbuf, out, b0);
    }
}

// Round 14
// 824.337 us; speedup vs baseline: 1.0946x; 1.0946x over previous
//
#include <hip/hip_runtime.h>
#include <hip/hip_bf16.h>
#include <stdint.h>

#define BTOT  65536
#define KTR   11
#define NSLOT 12   // 11 transforms + z

typedef __attribute__((ext_vector_type(8))) short bf16x8_t;
typedef __attribute__((ext_vector_type(4))) float f32x4_t;

// Swizzled LDS layout: row m x 256 bf16 cols, 16B groups rotated by row so
// frag ds_read_b128 across 16 rows spreads banks (<=2-way, free per m136).
__device__ __forceinline__ int act_addr(int m, int n) {
    return m * 256 + ((((n >> 3) + m) & 31) << 3) + (n & 7);
}

// tanh-form gelu via sigmoid identity: gelu = x * rcp(1 + 2^-t2).
__device__ __forceinline__ float gelu_fast(float x) {
    float x2 = x * x;
    float t2 = 2.3022083f * x * fmaf(0.044715f, x2, 1.0f);   // 1.5957691*log2e
    float e  = exp2f(-t2);
    return x * __builtin_amdgcn_rcpf(1.0f + e);
}

// generic fp32 -> bf16 cast, 4 elems/thread (also used for Tw2 cast)
__global__ void cast_x_kernel(const float* __restrict__ x, __hip_bfloat16* __restrict__ xb) {
    int i = (blockIdx.x * 256 + threadIdx.x) * 4;
    float4 v = *(const float4*)(x + i);
    union { __hip_bfloat16 h[4]; uint64_t u; } o;
    o.h[0] = __float2bfloat16(v.x);
    o.h[1] = __float2bfloat16(v.y);
    o.h[2] = __float2bfloat16(v.z);
    o.h[3] = __float2bfloat16(v.w);
    *(uint64_t*)(xb + i) = o.u;
}

// out[b][c][r] = in[b][r][c], cast fp32 -> bf16.
__global__ void transpose_cast_kernel(const float* __restrict__ in,
                                      __hip_bfloat16* __restrict__ out,
                                      int R, int C) {
    __shared__ float tile[32][33];
    int tpc = C >> 5;
    int tr = (blockIdx.x / tpc) << 5;
    int tc = (blockIdx.x % tpc) << 5;
    const float* bi = in + (size_t)blockIdx.y * R * C;
    __hip_bfloat16* bo = out + (size_t)blockIdx.y * R * C;
    int lx = threadIdx.x & 31, ly = threadIdx.x >> 5;
    #pragma unroll
    for (int r = 0; r < 32; r += 8)
        tile[ly + r][lx] = bi[(size_t)(tr + ly + r) * C + tc + lx];
    __syncthreads();
    #pragma unroll
    for (int r = 0; r < 32; r += 8)
        bo[(size_t)(tc + ly + r) * R + tr + lx] = __float2bfloat16(tile[lx][ly + r]);
}

// Fused weight: Wft[k][j][h] = sum_d Ew1t[j][d] * Tw2b[k][h][d]
// (= (Tw2[k] @ Ew1)^T). Legal: no nonlinearity between Tw2 and Ew1 stages.
__global__ void fuse_w_kernel(const __hip_bfloat16* __restrict__ Ew1t,
                              const __hip_bfloat16* __restrict__ Tw2b,
                              __hip_bfloat16* __restrict__ Wft)
{
    __shared__ __align__(16) __hip_bfloat16 bt[64 * 256];
    const int tid  = threadIdx.x;
    const int wave = tid >> 6, lane = tid & 63;
    const int lr = lane & 15, q = lane >> 4;
    const int k  = blockIdx.y;
    const int h0 = blockIdx.x << 6;
    const __hip_bfloat16* src = Tw2b + (size_t)k * 65536;

    #pragma unroll
    for (int i = 0; i < 8; ++i) {
        int lin = i * 256 + tid;
        int r = lin >> 5, g = lin & 31;
        bf16x8_t v = *(const bf16x8_t*)(src + (size_t)(h0 + r) * 256 + g * 8);
        *(bf16x8_t*)(bt + act_addr(r, g * 8)) = v;
    }
    __syncthreads();

    const int wc = wave << 6;
    f32x4_t acc[4][4];
    #pragma unroll
    for (int mt = 0; mt < 4; ++mt)
        #pragma unroll
        for (int nt = 0; nt < 4; ++nt)
            acc[mt][nt] = (f32x4_t){0.f, 0.f, 0.f, 0.f};

    #pragma unroll 1
    for (int kc = 0; kc < 8; ++kc) {
        const int kof = (kc << 5) + (q << 3);
        bf16x8_t a[4], b[4];
        #pragma unroll
        for (int mt = 0; mt < 4; ++mt)
            a[mt] = *(const bf16x8_t*)(Ew1t + (size_t)(wc + (mt << 4) + lr) * 256 + kof);
        #pragma unroll
        for (int nt = 0; nt < 4; ++nt)
            b[nt] = *(const bf16x8_t*)(bt + act_addr((nt << 4) + lr, kof));
        #pragma unroll
        for (int mt = 0; mt < 4; ++mt)
            #pragma unroll
            for (int nt = 0; nt < 4; ++nt)
                acc[mt][nt] = __builtin_amdgcn_mfma_f32_16x16x32_bf16(a[mt], b[nt], acc[mt][nt], 0, 0, 0);
    }

    __hip_bfloat16* dst = Wft + (size_t)k * 65536;
    #pragma unroll
    for (int mt = 0; mt < 4; ++mt)
        #pragma unroll
        for (int nt = 0; nt < 4; ++nt) {
            const int h = h0 + (nt << 4) + lr;
            #pragma unroll
            for (int r = 0; r < 4; ++r) {
                const int j = wc + (mt << 4) + (q << 2) + r;
                dst[(size_t)j * 256 + h] = __float2bfloat16(acc[mt][nt][r]);
            }
        }
}

// bf[k][j] = Eb1[j] + sum_d Tb2[k][d] * Ew1[d][j]   (fp32 throughout)
__global__ void fuse_b_kernel(const float* __restrict__ Tb2,
                              const float* __restrict__ Ew1,
                              const float* __restrict__ Eb1,
                              float* __restrict__ bf)
{
    const int k = blockIdx.x, j = threadIdx.x;
    float s = Eb1[j];
    #pragma unroll 4
    for (int d = 0; d < 256; ++d)
        s = fmaf(Tb2[k * 256 + d], Ew1[d * 256 + j], s);
    bf[k * 256 + j] = s;
}

// MFMA half of a stage: acc <- bias; acc += W^T x act^T over K=256.
// a-frags (global/L2) 1-deep prefetched across kc; b-frags in-loop from LDS
// (compiler's fine-grained lgkmcnt covers them; extra b-prefetch spilled, R10).
__device__ __forceinline__ void mfma_part(const __hip_bfloat16* act,
                                          const __hip_bfloat16* __restrict__ Wt,
                                          const float* __restrict__ bias,
                                          f32x4_t acc[4][4], int lr, int q, int wc)
{
    #pragma unroll
    for (int mt = 0; mt < 4; ++mt) {
        const float4 bv = *(const float4*)(bias + wc + (mt << 4) + (q << 2));
        #pragma unroll
        for (int nt = 0; nt < 4; ++nt)
            acc[mt][nt] = (f32x4_t){bv.x, bv.y, bv.z, bv.w};
    }

    bf16x8_t a[4];
    #pragma unroll
    for (int mt = 0; mt < 4; ++mt)
        a[mt] = *(const bf16x8_t*)(Wt + (size_t)(wc + (mt << 4) + lr) * 256 + (q << 3));

    #pragma unroll 1
    for (int kc = 0; kc < 8; ++kc) {
        const int kof = (kc << 5) + (q << 3);
        bf16x8_t an[4];
        if (kc < 7) {
            #pragma unroll
            for (int mt = 0; mt < 4; ++mt)
                an[mt] = *(const bf16x8_t*)(Wt + (size_t)(wc + (mt << 4) + lr) * 256 + kof + 32);
        }
        bf16x8_t b[4];
        #pragma unroll
        for (int nt = 0; nt < 4; ++nt)
            b[nt] = *(const bf16x8_t*)(act + act_addr((nt << 4) + lr, kof));
        #pragma unroll
        for (int mt = 0; mt < 4; ++mt)
            #pragma unroll
            for (int nt = 0; nt < 4; ++nt)
                acc[mt][nt] = __builtin_amdgcn_mfma_f32_16x16x32_bf16(a[mt], b[nt], acc[mt][nt], 0, 0, 0);
        if (kc < 7) {
            #pragma unroll
            for (int mt = 0; mt < 4; ++mt) a[mt] = an[mt];
        }
    }
}

// Epilogue half: gelu/cvt/swizzled ds_write of the 64 outputs.
template<bool DO_GELU>
__device__ __forceinline__ void ep_part(__hip_bfloat16* act, f32x4_t acc[4][4],
                                        int lr, int q, int wc)
{
    #pragma unroll
    for (int mt = 0; mt < 4; ++mt) {
        const int nbase = wc + (mt << 4) + (q << 2);
        #pragma unroll
        for (int nt = 0; nt < 4; ++nt) {
            const int row = (nt << 4) + lr;
            union { __hip_bfloat16 h[4]; uint64_t u; } o;
            #pragma unroll
            for (int r = 0; r < 4; ++r) {
                float v = acc[mt][nt][r];
                if (DO_GELU) v = gelu_fast(v);
                o.h[r] = __float2bfloat16(v);
            }
            *(uint64_t*)(act + act_addr(row, nbase)) = o.u;
        }
    }
}

// Paired-slot software-pipelined chain (R11, best-measured structure of the
// 7 variants tried; R13's wave-role-split regressed -> reverted). One block
// owns TWO slots of one tile, two act buffers, phases offset by half a
// stage so each phase co-issues mfma(one slot) with epilogue(other slot).
// 7 barriers per 6 stages. Plateau analysis: chain MFMA-busy ~= theoretical
// minimum; residual is ep-VALU + barrier drain + latency at 2 blocks/CU.
__launch_bounds__(256, 2)
__global__ void chain_kernel(const __hip_bfloat16* __restrict__ xb,
                             const __hip_bfloat16* __restrict__ Tw1t,
                             const float* __restrict__ Tb1,
                             const __hip_bfloat16* __restrict__ Wft,
                             const float* __restrict__ bfb,
                             const __hip_bfloat16* __restrict__ Ew1t,
                             const float* __restrict__ Eb1,
                             const __hip_bfloat16* __restrict__ Ew2t,
                             const float* __restrict__ Eb2,
                             __hip_bfloat16* __restrict__ zbuf,
                             int b0)
{
    __shared__ __align__(16) __hip_bfloat16 actA[64 * 256];   // 32 KB
    __shared__ __align__(16) __hip_bfloat16 actB[64 * 256];   // 32 KB
    const int tid  = threadIdx.x;
    const int wave = tid >> 6, lane = tid & 63;
    const int lr = lane & 15, q = lane >> 4, wc = wave << 6;
    const int pair = blockIdx.y;
    const int tile = blockIdx.x;
    const int s0 = pair * 2, s1 = s0 + 1;
    const bool zp = (pair == 5);          // s1 == 11 is the z (encoder) slot

    // stage x tile into BOTH buffers
    #pragma unroll
    for (int i = 0; i < 8; ++i) {
        int lin = i * 256 + tid;
        int r = lin >> 5, g = lin & 31;
        bf16x8_t v = *(const bf16x8_t*)(xb + (size_t)(b0 + tile * 64 + r) * 256 + g * 8);
        *(bf16x8_t*)(actA + act_addr(r, g * 8)) = v;
        *(bf16x8_t*)(actB + act_addr(r, g * 8)) = v;
    }
    __syncthreads();

    // stage tables: A = slot s0 (always a T-slot), B = slot s1 (T or z)
    const __hip_bfloat16* WA0 = Tw1t + (size_t)s0 * 65536;
    const __hip_bfloat16* WA1 = Wft  + (size_t)s0 * 65536;
    const float* BA0 = Tb1 + s0 * 256;
    const float* BA1 = bfb + s0 * 256;
    const __hip_bfloat16* WB0 = zp ? Ew1t : Tw1t + (size_t)s1 * 65536;
    const __hip_bfloat16* WB1 = zp ? Ew2t : Wft  + (size_t)s1 * 65536;
    const float* BB0 = zp ? Eb1 : Tb1 + s1 * 256;
    const float* BB1 = zp ? Eb2 : bfb + s1 * 256;

    f32x4_t accA[4][4], accB[4][4];

    // ph0: warm A
    mfma_part(actA, WA0, BA0, accA, lr, q, wc);
    __syncthreads();
    // ph1: mfma B0 || ep A0 (gelu)
    mfma_part(actB, WB0, BB0, accB, lr, q, wc);
    ep_part<true>(actA, accA, lr, q, wc);
    __syncthreads();
    // ph2: mfma A1 || ep B0 (gelu for both T and z first stages)
    mfma_part(actA, WA1, BA1, accA, lr, q, wc);
    ep_part<true>(actB, accB, lr, q, wc);
    __syncthreads();
    // ph3: mfma B1 || ep A1 (gelu)
    mfma_part(actB, WB1, BB1, accB, lr, q, wc);
    ep_part<true>(actA, accA, lr, q, wc);
    __syncthreads();
    // ph4: mfma A2 (Ew2) || ep B1 (T: gelu; z: final, no gelu)
    mfma_part(actA, Ew2t, Eb2, accA, lr, q, wc);
    if (zp) ep_part<false>(actB, accB, lr, q, wc);
    else    ep_part<true >(actB, accB, lr, q, wc);
    __syncthreads();
    // ph5: (T-pair) mfma B2 (Ew2) || ep A2 (no gelu)
    if (!zp) mfma_part(actB, Ew2t, Eb2, accB, lr, q, wc);
    ep_part<false>(actA, accA, lr, q, wc);
    __syncthreads();
    // ph6: (T-pair) ep B2 (no gelu)
    if (!zp) {
        ep_part<false>(actB, accB, lr, q, wc);
        __syncthreads();
    }

    // contiguous per-slot zbuf blobs: zbuf[tile][slot][64][256], nontemporal
    __hip_bfloat16* d0 = zbuf + (size_t)(tile * NSLOT + s0) * (64 * 256);
    __hip_bfloat16* d1 = zbuf + (size_t)(tile * NSLOT + s1) * (64 * 256);
    #pragma unroll
    for (int i = 0; i < 8; ++i) {
        int lin = i * 256 + tid;
        int r = lin >> 5, g = lin & 31;
        bf16x8_t v0 = *(const bf16x8_t*)(actA + act_addr(r, g * 8));
        __builtin_nontemporal_store(v0, (bf16x8_t*)(d0 + lin * 8));
        bf16x8_t v1 = *(const bf16x8_t*)(actB + act_addr(r, g * 8));
        __builtin_nontemporal_store(v1, (bf16x8_t*)(d1 + lin * 8));
    }
}

// Per row: G = Z Z^T (12x12 over H=256) via mfma(v,v,acc). 8 rows/wave,
// 2-deep row pipeline, rcp-for-divide tail, nontemporal blob reads.
#define ROW_BODY(V, I)                                                        \
    {                                                                         \
        f32x4_t acc = (f32x4_t){0.f, 0.f, 0.f, 0.f};                          \
        _Pragma("unroll")                                                     \
        for (int kc = 0; kc < 8; ++kc)                                        \
            acc = __builtin_amdgcn_mfma_f32_16x16x32_bf16(V[kc], V[kc], acc, 0, 0, 0); \
        _Pragma("unroll")                                                     \
        for (int rr = 0; rr < 4; ++rr)                                        \
            Gw[wave][(q << 2) + rr][lr] = acc[rr];                            \
        float term = 0.f;                                                     \
        if (lane < 11) {                                                      \
            const int k = lane;                                               \
            float nr[NSLOT];                                                  \
            _Pragma("unroll")                                                 \
            for (int l = 0; l < NSLOT; ++l)                                   \
                nr[l] = __builtin_amdgcn_rcpf(fmaxf(sqrtf(Gw[wave][l][l]), 1e-4f)); \
            const float nrk = nr[k];                                          \
            float neg = 0.f;                                                  \
            _Pragma("unroll")                                                 \
            for (int l = 0; l < KTR; ++l)                                     \
                if (l != k)                                                   \
                    neg += __expf(Gw[wave][l][k] * nr[l] * nrk);              \
            float cz = Gw[wave][KTR][k] * nr[KTR] * nrk;                      \
            term = __logf(__expf(cz) + neg) - cz;                             \
        }                                                                     \
        term += __shfl_xor(term, 1);                                          \
        term += __shfl_xor(term, 2);                                          \
        term += __shfl_xor(term, 4);                                          \
        term += __shfl_xor(term, 8);                                          \
        if (lane == 0) out[b0 + r0 + (I)] = term;                             \
    }

__launch_bounds__(256, 4)
__global__ void reduce_kernel(const __hip_bfloat16* __restrict__ zbuf,
                              float* __restrict__ out, int b0)
{
    __shared__ float Gw[4][16][17];
    const int tid  = threadIdx.x;
    const int wave = tid >> 6, lane = tid & 63;
    const int lr = lane & 15, q = lane >> 4;
    const int slot = lr < NSLOT ? lr : NSLOT - 1;   // lanes 12-15 broadcast slot 11

    const int r0   = (blockIdx.x * 4 + wave) * 8;   // 8 contiguous rows per wave
    const int tile = r0 >> 6, rloc = r0 & 63;       // all 8 rows inside one tile blob
    const __hip_bfloat16* zr = zbuf + (size_t)tile * (NSLOT * 64 * 256)
                             + (size_t)slot * (64 * 256) + rloc * 256 + (q << 3);

    bf16x8_t va[8], vb[8];
    #pragma unroll
    for (int kc = 0; kc < 8; ++kc)
        va[kc] = __builtin_nontemporal_load((const bf16x8_t*)(zr + kc * 32));

    #pragma unroll 1
    for (int i2 = 0; i2 < 4; ++i2) {
        const int ie = i2 * 2;
        {   // even row: consume va, prefetch row ie+1 into vb (always valid)
            const __hip_bfloat16* zn = zr + (ie + 1) * 256;
            #pragma unroll
            for (int kc = 0; kc < 8; ++kc)
                vb[kc] = __builtin_nontemporal_load((const bf16x8_t*)(zn + kc * 32));
            ROW_BODY(va, ie)
        }
        {   // odd row: consume vb, prefetch row ie+2 into va (guarded)
            if (ie + 2 < 8) {
                const __hip_bfloat16* zn = zr + (ie + 2) * 256;
                #pragma unroll
                for (int kc = 0; kc < 8; ++kc)
                    va[kc] = __builtin_nontemporal_load((const bf16x8_t*)(zn + kc * 32));
            }
            ROW_BODY(vb, ie + 1)
        }
    }
}

extern "C" void kernel_launch(void* const* d_in, const int* in_sizes, int n_in,
                              void* d_out, int out_size, void* d_ws, size_t ws_size,
                              hipStream_t stream)
{
    const float* x   = (const float*)d_in[0];
    const float* Tw1 = (const float*)d_in[1];
    const float* Tb1 = (const float*)d_in[2];
    const float* Tw2 = (const float*)d_in[3];
    const float* Tb2 = (const float*)d_in[4];
    const float* Ew1 = (const float*)d_in[5];
    const float* Eb1 = (const float*)d_in[6];
    const float* Ew2 = (const float*)d_in[7];
    const float* Eb2 = (const float*)d_in[8];
    float* out = (float*)d_out;

    char* ws = (char*)d_ws;
    const size_t off_xb   = 0;
    const size_t off_tw1  = off_xb   + (size_t)BTOT * 256 * 2;     // 32 MB
    const size_t off_wf   = off_tw1  + (size_t)KTR * 65536 * 2;
    const size_t off_ew1  = off_wf   + (size_t)KTR * 65536 * 2;
    const size_t off_ew2  = off_ew1  + (size_t)65536 * 2;
    const size_t off_tw2b = off_ew2  + (size_t)65536 * 2;
    const size_t off_bf   = off_tw2b + (size_t)KTR * 65536 * 2;
    const size_t off_z    = off_bf   + (size_t)KTR * 256 * 4;

    __hip_bfloat16* xb   = (__hip_bfloat16*)(ws + off_xb);
    __hip_bfloat16* Tw1t = (__hip_bfloat16*)(ws + off_tw1);
    __hip_bfloat16* Wft  = (__hip_bfloat16*)(ws + off_wf);
    __hip_bfloat16* Ew1t = (__hip_bfloat16*)(ws + off_ew1);
    __hip_bfloat16* Ew2t = (__hip_bfloat16*)(ws + off_ew2);
    __hip_bfloat16* Tw2b = (__hip_bfloat16*)(ws + off_tw2b);
    float*          bfb  = (float*)(ws + off_bf);
    __hip_bfloat16* zbuf = (__hip_bfloat16*)(ws + off_z);

    // 2-chunk split: zbuf/chunk = 201MB (proven fine in R6 even without nt
    // streams + blob layout). Halves the loop's launch gaps and per-dispatch
    // wind-down tails vs 4 chunks; kernel code identical to the best-total
    // R11 configuration.
    long long zbytes = (long long)ws_size - (long long)off_z;
    long long rows_cap = zbytes > 0 ? zbytes / ((long long)NSLOT * 256 * 2) : 0;
    int chunk = (int)((rows_cap / 128) * 128);
    if (chunk > BTOT / 2) chunk = BTOT / 2;
    if (chunk < 128) chunk = 128;

    cast_x_kernel<<<dim3(BTOT * 256 / 1024), 256, 0, stream>>>(x, xb);
    cast_x_kernel<<<dim3(KTR * 65536 / 1024), 256, 0, stream>>>(Tw2, Tw2b);
    transpose_cast_kernel<<<dim3(64, KTR), 256, 0, stream>>>(Tw1, Tw1t, 256, 256);
    transpose_cast_kernel<<<dim3(64, 1),   256, 0, stream>>>(Ew1, Ew1t, 256, 256);
    transpose_cast_kernel<<<dim3(64, 1),   256, 0, stream>>>(Ew2, Ew2t, 256, 256);
    fuse_b_kernel<<<dim3(KTR), 256, 0, stream>>>(Tb2, Ew1, Eb1, bfb);
    fuse_w_kernel<<<dim3(4, KTR), 256, 0, stream>>>(Ew1t, Tw2b, Wft);

    for (int b0 = 0; b0 < BTOT; b0 += chunk) {
        int rows = (BTOT - b0 < chunk) ? (BTOT - b0) : chunk;
        chain_kernel<<<dim3(rows / 64, NSLOT / 2), 256, 0, stream>>>(
            xb, Tw1t, Tb1, Wft, bfb, Ew1t, Eb1, Ew2t, Eb2, zbuf, b0);
        reduce_kernel<<<dim3(rows / 32), 256, 0, stream>>>(zbuf, out, b0);
    }
}